// Round 6
// baseline (8498.537 us; speedup 1.0000x reference)
//
#include <hip/hip_runtime.h>

using u16    = unsigned short;
using u64_t  = unsigned long long;
using short8 = __attribute__((ext_vector_type(8))) short;
using f32x4  = __attribute__((ext_vector_type(4))) float;

#define T_STEPS 512
#define BATCH   128
#define HDIM    512
#define EDIM    256
#define NWG     256
#define WGS     256

__device__ __forceinline__ u16 f2bf(float f) {
  unsigned u = __float_as_uint(f);
  u += 0x7FFFu + ((u >> 16) & 1u);   // RNE
  return (u16)(u >> 16);
}
__device__ __forceinline__ float bf2f(u16 h) {
  return __uint_as_float(((unsigned)h) << 16);
}
__device__ __forceinline__ float sigm(float x) { return 1.0f / (1.0f + __expf(-x)); }
__device__ __forceinline__ float ftanh(float x) { return 1.0f - 2.0f / (__expf(2.0f * x) + 1.0f); }

// sc1 write-through store: h becomes globally visible at the LLC.
__device__ __forceinline__ void cstore2(u16* p, u16 v) {
  __hip_atomic_store(p, v, __ATOMIC_RELAXED, __HIP_MEMORY_SCOPE_AGENT);
}

// Dependent-FMA spin fillers: keep the VALU issuing (anti-downclock) and
// throttle poll rate.
__device__ __forceinline__ void spin_filler32() {
  float a = 1.0f, b = 1.0000001f;
  #pragma unroll
  for (int z = 0; z < 32; ++z)
    asm volatile("v_fmac_f32 %0, %1, %2" : "+v"(a) : "v"(b), "v"(b));
}
__device__ __forceinline__ void spin_filler8() {
  float a = 1.0f, b = 1.0000001f;
  #pragma unroll
  for (int z = 0; z < 8; ++z)
    asm volatile("v_fmac_f32 %0, %1, %2" : "+v"(a) : "v"(b), "v"(b));
}

// ---------------- x -> bf16 prep ----------------
__global__ void cvt_bf16_kernel(const float* __restrict__ src, u16* __restrict__ dst, int n4) {
  int i = blockIdx.x * blockDim.x + threadIdx.x;
  if (i >= n4) return;
  float4 v = ((const float4*)src)[i];
  uint2 o;
  o.x = (unsigned)f2bf(v.x) | ((unsigned)f2bf(v.y) << 16);
  o.y = (unsigned)f2bf(v.z) | ((unsigned)f2bf(v.w) << 16);
  ((uint2*)dst)[i] = o;
}

// ---------------- grid barrier: 2-level arrival tree + busy-issue waits ----------------
// Entry __syncthreads drains vmcnt(0) per wave, so all sc1 h-stores are LLC-visible
// before tid0's arrival add. DEADLOCK-SAFE wait structure:
//  - wave 0: tid0 does arrival adds (finite divergence), then ALL 64 lanes poll the
//    global release word together (wave-uniform loop; one coalesced load per poll);
//    lane 0 then publishes to the LDS flag.
//  - waves 1..3: spin on the LDS flag (inter-wave producer-consumer: safe).
// No s_sleep, no long s_barrier block -> SCLK should stay up.
__device__ __forceinline__ void grid_barrier(int* cnt, int* root, int* rel,
                                             volatile int* barflag, int it,
                                             int tid, int w, int bid) {
  __syncthreads();
  if (w == 0) {
    if (tid == 0) {
      int* mycnt = cnt + (bid >> 5) * 64;   // 8 sub-counters, 256B apart
      int old = __hip_atomic_fetch_add(mycnt, 1, __ATOMIC_RELAXED, __HIP_MEMORY_SCOPE_AGENT);
      if (old == 32 * (it + 1) - 1) {
        int r = __hip_atomic_fetch_add(root, 1, __ATOMIC_RELAXED, __HIP_MEMORY_SCOPE_AGENT);
        if (r == 8 * (it + 1) - 1)
          __hip_atomic_store(rel, it + 1, __ATOMIC_RELAXED, __HIP_MEMORY_SCOPE_AGENT);
      }
    }
    // wave-uniform poll: all lanes read the same address -> one request per poll
    while (__hip_atomic_load(rel, __ATOMIC_RELAXED, __HIP_MEMORY_SCOPE_AGENT) < it + 1)
      spin_filler32();
    if (tid == 0) *barflag = it + 1;        // LDS broadcast to sibling waves
  } else {
    while (*barflag < it + 1)
      spin_filler8();
  }
}

// ---------------- persistent 2-layer LSTM ----------------
// WG tile: 64 batch rows (mhalf) x 8 h-cols (nc) -> 32 gate rows [i(8) f(8) g(8) o(8)].
// LDS: Ws_in [K_in/8][32][8] bf16 (32KB), Ws_rec [64][32][8] bf16 (32KB) = 64KB dynamic.
__global__ void __launch_bounds__(WGS, 1) lstm_kernel(
    const float* __restrict__ wih0, const float* __restrict__ whh0,
    const float* __restrict__ bih0, const float* __restrict__ bhh0,
    const float* __restrict__ wih1, const float* __restrict__ whh1,
    const float* __restrict__ bih1, const float* __restrict__ bhh1,
    const float* __restrict__ wfc,  const float* __restrict__ bfc,
    const u16* __restrict__ xbf, u16* __restrict__ h0buf, u16* __restrict__ h1buf,
    float* __restrict__ out, int* cnt, int* root, int* rel)
{
  extern __shared__ u16 smem[];
  u16* Ws_in  = smem;            // [K_in/8][32][8]
  u16* Ws_rec = smem + 16384;    // [64][32][8]
  __shared__ int barflag;

  const int tid    = threadIdx.x;
  const int bid    = blockIdx.x;
  const int layer  = bid >> 7;          // 0..1
  const int lb     = bid & 127;
  const int mhalf  = lb & 1;            // batch half
  const int nc     = lb >> 1;           // 0..63 -> 8 h-cols each
  const int jbase  = nc * 8;
  const int w      = tid >> 6;          // wave 0..3 -> 16 batch rows each
  const int lane   = tid & 63;
  const int l15    = lane & 15;
  const int q      = lane >> 4;
  const int wmbase = mhalf * 64 + w * 16;

  if (tid == 0) barflag = 0;

  const int K_in = layer ? HDIM : EDIM;
  const float* Wih = layer ? wih1 : wih0;
  const float* Whh = layer ? whh1 : whh0;
  const float* Bih = layer ? bih1 : bih0;
  const float* Bhh = layer ? bhh1 : bhh0;

  // ---- one-time: stage weight slices to LDS as bf16, layout [k/8][n][8] ----
  for (int p = tid; p < 32 * (K_in / 8); p += WGS) {
    int c = p >> 5, n = p & 31;
    int grow = (n >> 3) * HDIM + jbase + (n & 7);     // gate*512 + col
    const float* s = Wih + (size_t)grow * K_in + c * 8;
    u16* d = Ws_in + p * 8;
    #pragma unroll
    for (int e = 0; e < 8; ++e) d[e] = f2bf(s[e]);
  }
  for (int p = tid; p < 32 * (HDIM / 8); p += WGS) {
    int c = p >> 5, n = p & 31;
    int grow = (n >> 3) * HDIM + jbase + (n & 7);
    const float* s = Whh + (size_t)grow * HDIM + c * 8;
    u16* d = Ws_rec + p * 8;
    #pragma unroll
    for (int e = 0; e < 8; ++e) d[e] = f2bf(s[e]);
  }

  // per-lane biases for column cc = l15&7 (lanes n and n+8 duplicate the same column)
  const int cc = l15 & 7;
  const float bi_i = Bih[0*HDIM + jbase + cc] + Bhh[0*HDIM + jbase + cc];
  const float bi_f = Bih[1*HDIM + jbase + cc] + Bhh[1*HDIM + jbase + cc];
  const float bi_g = Bih[2*HDIM + jbase + cc] + Bhh[2*HDIM + jbase + cc];
  const float bi_o = Bih[3*HDIM + jbase + cc] + Bhh[3*HDIM + jbase + cc];

  __syncthreads();

  float cst[4] = {0.f, 0.f, 0.f, 0.f};   // c-state: 4 rows (q*4+r) x col cc
  u16* ownbuf = layer ? h1buf : h0buf;
  const int arow = wmbase + l15;

  for (int it = 0; it <= T_STEPS; ++it) {
    const int t = layer ? (it - 1) : it;
    if (t >= 0 && t < T_STEPS) {
      // Acquire: invalidate stale L1/L2 lines (no writeback) so plain loads below
      // see the h-state published (sc1 write-through) before the last barrier.
      __builtin_amdgcn_fence(__ATOMIC_ACQUIRE, "agent");

      f32x4 acc0 = {0.f, 0.f, 0.f, 0.f};   // cols n=0..15  (i|f)
      f32x4 acc1 = {0.f, 0.f, 0.f, 0.f};   // cols n=16..31 (g|o)

      auto MM2 = [&](short8 a, const u16* Ws, int kk) {
        const u16* bb = Ws + (kk * 4 + q) * 256 + l15 * 8;
        short8 b0 = *(const short8*)bb;
        short8 b1 = *(const short8*)(bb + 128);
        acc0 = __builtin_amdgcn_mfma_f32_16x16x32_bf16(a, b0, acc0, 0, 0, 0);
        acc1 = __builtin_amdgcn_mfma_f32_16x16x32_bf16(a, b1, acc1, 0, 0, 0);
      };

      // input GEMM (plain loads; L2-cached, fresh after the acquire fence)
      if (layer == 0) {
        const u16* abase = xbf + ((size_t)arow * T_STEPS + t) * EDIM + q * 8;
        #pragma unroll
        for (int kk = 0; kk < EDIM / 32; ++kk) MM2(*(const short8*)(abase + kk * 32), Ws_in, kk);
      } else {
        const u16* abase = h0buf + (size_t)(t & 1) * (BATCH * HDIM) + (size_t)arow * HDIM + q * 8;
        #pragma unroll
        for (int kk = 0; kk < HDIM / 32; ++kk) MM2(*(const short8*)(abase + kk * 32), Ws_in, kk);
      }
      // recurrent GEMM (h_{t-1}; t==0 -> h=0, skip)
      if (t > 0) {
        const u16* rbase = ownbuf + (size_t)((t - 1) & 1) * (BATCH * HDIM) + (size_t)arow * HDIM + q * 8;
        #pragma unroll
        for (int kk = 0; kk < HDIM / 32; ++kk) MM2(*(const short8*)(rbase + kk * 32), Ws_rec, kk);
      }

      // ---- gate epilogue: D layout col=lane&15,row=q*4+r; lanes n<8 hold i,g; n>=8 hold f,o ----
      u16* hw = ownbuf + (size_t)(t & 1) * (BATCH * HDIM);
      const bool low = (l15 < 8);
      #pragma unroll
      for (int r = 0; r < 4; ++r) {
        float a0 = acc0[r], a1 = acc1[r];
        float p0 = __shfl_xor(a0, 8);
        float p1 = __shfl_xor(a1, 8);
        float iv = low ? a0 : p0;
        float fv = low ? p0 : a0;
        float gv = low ? a1 : p1;
        float ov = low ? p1 : a1;
        iv = sigm(iv + bi_i);
        fv = sigm(fv + bi_f);
        gv = ftanh(gv + bi_g);
        ov = sigm(ov + bi_o);
        float cn = fv * cst[r] + iv * gv;
        cst[r] = cn;
        float hv = ov * ftanh(cn);
        if (low) cstore2(&hw[(size_t)(wmbase + q * 4 + r) * HDIM + jbase + cc], f2bf(hv));
      }
    }
    grid_barrier(cnt, root, rel, &barflag, it, tid, w, bid);
  }

  // ---- FC epilogue: out[b] = sigmoid(h2[b,:] . w_fc + b_fc); h1_t=511 is in parity 1 ----
  if (bid == NWG - 1) {
    __builtin_amdgcn_fence(__ATOMIC_ACQUIRE, "agent");
    const int b = tid >> 1, half = tid & 1;
    const u16* hp = h1buf + (size_t)1 * (BATCH * HDIM) + (size_t)b * HDIM + half * 256;
    const float* wf = wfc + half * 256;
    float s = 0.f;
    for (int k = 0; k < 256; ++k) s += bf2f(hp[k]) * wf[k];
    s += __shfl_xor(s, 1);
    if (half == 0) out[b] = sigm(s + bfc[0]);
  }
}

extern "C" void kernel_launch(void* const* d_in, const int* in_sizes, int n_in,
                              void* d_out, int out_size, void* d_ws, size_t ws_size,
                              hipStream_t stream) {
  (void)in_sizes; (void)n_in; (void)out_size; (void)ws_size;
  const float* x    = (const float*)d_in[0];
  const float* wih0 = (const float*)d_in[1];
  const float* whh0 = (const float*)d_in[2];
  const float* bih0 = (const float*)d_in[3];
  const float* bhh0 = (const float*)d_in[4];
  const float* wih1 = (const float*)d_in[5];
  const float* whh1 = (const float*)d_in[6];
  const float* bih1 = (const float*)d_in[7];
  const float* bhh1 = (const float*)d_in[8];
  const float* wfc  = (const float*)d_in[9];
  const float* bfc  = (const float*)d_in[10];
  float* outp = (float*)d_out;

  char* ws = (char*)d_ws;
  int*  cnt  = (int*)ws;                                       // 8 sub-counters, 256B apart
  int*  root = (int*)(ws + 2048);                              // root counter
  int*  rel  = (int*)(ws + 2176);                              // release epoch word
  u16*  xbf  = (u16*)(ws + 4096);                              // 128*512*256 bf16 = 32 MiB
  u16*  h0   = (u16*)(ws + 4096 + 33554432);                   // [2][128][512] bf16
  u16*  h1   = h0 + 2 * BATCH * HDIM;                          // [2][128][512] bf16

  hipMemsetAsync(d_ws, 0, 4096, stream);                       // zero barrier state

  const int n4 = (BATCH * T_STEPS * EDIM) / 4;                 // 4,194,304
  cvt_bf16_kernel<<<n4 / 256, 256, 0, stream>>>(x, xbf, n4);

  hipFuncSetAttribute((const void*)lstm_kernel,
                      hipFuncAttributeMaxDynamicSharedMemorySize, 65536);

  void* args[] = { (void*)&wih0, (void*)&whh0, (void*)&bih0, (void*)&bhh0,
                   (void*)&wih1, (void*)&whh1, (void*)&bih1, (void*)&bhh1,
                   (void*)&wfc,  (void*)&bfc,
                   (void*)&xbf,  (void*)&h0,   (void*)&h1,
                   (void*)&outp, (void*)&cnt,  (void*)&root, (void*)&rel };
  hipLaunchCooperativeKernel((void*)lstm_kernel, dim3(NWG), dim3(WGS),
                             args, 65536, stream);
}

// Round 7
// 5476.017 us; speedup vs baseline: 1.5520x; 1.5520x over previous
//
#include <hip/hip_runtime.h>

using u16    = unsigned short;
using u64_t  = unsigned long long;
using short4v = __attribute__((ext_vector_type(4))) short;
using short8 = __attribute__((ext_vector_type(8))) short;
using f32x4  = __attribute__((ext_vector_type(4))) float;

#define T_STEPS 512
#define BATCH   128
#define HDIM    512
#define EDIM    256
#define NWG     256
#define WGS     256
#define SLOT    (BATCH * HDIM)

__device__ __forceinline__ u16 f2bf(float f) {
  unsigned u = __float_as_uint(f);
  u += 0x7FFFu + ((u >> 16) & 1u);   // RNE
  return (u16)(u >> 16);
}
__device__ __forceinline__ float bf2f(u16 h) {
  return __uint_as_float(((unsigned)h) << 16);
}
__device__ __forceinline__ float sigm(float x) { return 1.0f / (1.0f + __expf(-x)); }
__device__ __forceinline__ float ftanh(float x) { return 1.0f - 2.0f / (__expf(2.0f * x) + 1.0f); }

// ---- coherent (agent-scope, sc0|sc1) accessors: LLC-coherent, no L2 flush ----
__device__ __forceinline__ u64_t cl8(const u16* p) {
  return __hip_atomic_load((const u64_t*)p, __ATOMIC_RELAXED, __HIP_MEMORY_SCOPE_AGENT);
}
__device__ __forceinline__ void cstore2(u16* p, u16 v) {
  __hip_atomic_store(p, v, __ATOMIC_RELAXED, __HIP_MEMORY_SCOPE_AGENT);
}
__device__ __forceinline__ short8 mk8(u64_t lo, u64_t hi) {
  short4v a = __builtin_bit_cast(short4v, lo);
  short4v b = __builtin_bit_cast(short4v, hi);
  return __builtin_shufflevector(a, b, 0, 1, 2, 3, 4, 5, 6, 7);
}

// ---------------- x -> bf16 prep ----------------
__global__ void cvt_bf16_kernel(const float* __restrict__ src, u16* __restrict__ dst, int n4) {
  int i = blockIdx.x * blockDim.x + threadIdx.x;
  if (i >= n4) return;
  float4 v = ((const float4*)src)[i];
  uint2 o;
  o.x = (unsigned)f2bf(v.x) | ((unsigned)f2bf(v.y) << 16);
  o.y = (unsigned)f2bf(v.z) | ((unsigned)f2bf(v.w) << 16);
  ((uint2*)dst)[i] = o;
}

// ---------------- grid barrier: arrival tree + release word ----------------
// Entry __syncthreads drains vmcnt(0) per wave -> all sc1 h-stores are LLC-visible
// before tid0's arrival add. tid0 polls the release word with s_sleep(1); sibling
// waves wait at the exit s_barrier. Monotone epochs; no re-arm.
__device__ __forceinline__ void grid_barrier(int* cnt, int* root, int* rel,
                                             int it, int tid, int bid) {
  __syncthreads();
  if (tid == 0) {
    int* mycnt = cnt + (bid >> 5) * 64;   // 8 sub-counters, 256B apart
    int old = __hip_atomic_fetch_add(mycnt, 1, __ATOMIC_RELAXED, __HIP_MEMORY_SCOPE_AGENT);
    if (old == 32 * (it + 1) - 1) {
      int r = __hip_atomic_fetch_add(root, 1, __ATOMIC_RELAXED, __HIP_MEMORY_SCOPE_AGENT);
      if (r == 8 * (it + 1) - 1)
        __hip_atomic_store(rel, it + 1, __ATOMIC_RELAXED, __HIP_MEMORY_SCOPE_AGENT);
    }
    while (__hip_atomic_load(rel, __ATOMIC_RELAXED, __HIP_MEMORY_SCOPE_AGENT) < it + 1)
      __builtin_amdgcn_s_sleep(1);
  }
  __syncthreads();
}

// ---------------- persistent 2-layer LSTM ----------------
// WG tile: 64 batch rows (mhalf) x 8 h-cols (nc) -> 32 gate rows [i(8) f(8) g(8) o(8)].
// LDS: Ws_in [K_in/8][32][8] bf16 (32KB), Ws_rec [64][32][8] bf16 (32KB) = 64KB dynamic.
__global__ void __launch_bounds__(WGS, 1) lstm_kernel(
    const float* __restrict__ wih0, const float* __restrict__ whh0,
    const float* __restrict__ bih0, const float* __restrict__ bhh0,
    const float* __restrict__ wih1, const float* __restrict__ whh1,
    const float* __restrict__ bih1, const float* __restrict__ bhh1,
    const float* __restrict__ wfc,  const float* __restrict__ bfc,
    const u16* __restrict__ xbf, u16* __restrict__ h0buf, u16* __restrict__ h1buf,
    float* __restrict__ out, int* cnt, int* root, int* rel)
{
  extern __shared__ u16 smem[];
  u16* Ws_in  = smem;            // [K_in/8][32][8]
  u16* Ws_rec = smem + 16384;    // [64][32][8]

  const int tid    = threadIdx.x;
  const int bid    = blockIdx.x;
  const int layer  = bid >> 7;          // 0..1
  const int lb     = bid & 127;
  const int mhalf  = lb & 1;            // batch half
  const int nc     = lb >> 1;           // 0..63 -> 8 h-cols each
  const int jbase  = nc * 8;
  const int w      = tid >> 6;          // wave 0..3 -> 16 batch rows each
  const int lane   = tid & 63;
  const int l15    = lane & 15;
  const int q      = lane >> 4;
  const int wmbase = mhalf * 64 + w * 16;

  const int K_in = layer ? HDIM : EDIM;
  const float* Wih = layer ? wih1 : wih0;
  const float* Whh = layer ? whh1 : whh0;
  const float* Bih = layer ? bih1 : bih0;
  const float* Bhh = layer ? bhh1 : bhh0;

  // ---- one-time: stage weight slices to LDS as bf16, layout [k/8][n][8] ----
  for (int p = tid; p < 32 * (K_in / 8); p += WGS) {
    int c = p >> 5, n = p & 31;
    int grow = (n >> 3) * HDIM + jbase + (n & 7);     // gate*512 + col
    const float* s = Wih + (size_t)grow * K_in + c * 8;
    u16* d = Ws_in + p * 8;
    #pragma unroll
    for (int e = 0; e < 8; ++e) d[e] = f2bf(s[e]);
  }
  for (int p = tid; p < 32 * (HDIM / 8); p += WGS) {
    int c = p >> 5, n = p & 31;
    int grow = (n >> 3) * HDIM + jbase + (n & 7);
    const float* s = Whh + (size_t)grow * HDIM + c * 8;
    u16* d = Ws_rec + p * 8;
    #pragma unroll
    for (int e = 0; e < 8; ++e) d[e] = f2bf(s[e]);
  }

  // per-lane biases for column cc = l15&7 (lanes n and n+8 duplicate the same column)
  const int cc = l15 & 7;
  const float bi_i = Bih[0*HDIM + jbase + cc] + Bhh[0*HDIM + jbase + cc];
  const float bi_f = Bih[1*HDIM + jbase + cc] + Bhh[1*HDIM + jbase + cc];
  const float bi_g = Bih[2*HDIM + jbase + cc] + Bhh[2*HDIM + jbase + cc];
  const float bi_o = Bih[3*HDIM + jbase + cc] + Bhh[3*HDIM + jbase + cc];

  __syncthreads();

  float cst[4] = {0.f, 0.f, 0.f, 0.f};   // c-state: 4 rows (q*4+r) x col cc
  u16* ownbuf = layer ? h1buf : h0buf;
  const int arow = wmbase + l15;

  for (int it = 0; it <= T_STEPS; ++it) {
    const int t = layer ? (it - 1) : it;
    if (t >= 0 && t < T_STEPS) {
      // ======== BATCHED LOAD PHASE: all h-frag loads issued back-to-back ========
      u64_t ilo[16], ihi[16];   // input-GEMM frags (layer 1 only; layer 0 uses xfr)
      u64_t rlo[16], rhi[16];   // recurrent frags
      short8 xfr[8];            // layer-0 x frags (plain cached loads)

      if (layer == 1) {
        const u16* ab = h0buf + (size_t)(t & 1) * SLOT + (size_t)arow * HDIM + q * 8;
        #pragma unroll
        for (int kk = 0; kk < 16; ++kk) {
          ilo[kk] = cl8(ab + kk * 32);
          ihi[kk] = cl8(ab + kk * 32 + 4);
        }
      }
      if (t > 0) {
        const u16* rb = ownbuf + (size_t)((t - 1) & 1) * SLOT + (size_t)arow * HDIM + q * 8;
        #pragma unroll
        for (int kk = 0; kk < 16; ++kk) {
          rlo[kk] = cl8(rb + kk * 32);
          rhi[kk] = cl8(rb + kk * 32 + 4);
        }
      }
      if (layer == 0) {
        const u16* xb = xbf + ((size_t)arow * T_STEPS + t) * EDIM + q * 8;
        #pragma unroll
        for (int kk = 0; kk < 8; ++kk) xfr[kk] = *(const short8*)(xb + kk * 32);
      }

      // ======== MFMA PHASE ========
      f32x4 acc0 = {0.f, 0.f, 0.f, 0.f};   // cols n=0..15  (i|f)
      f32x4 acc1 = {0.f, 0.f, 0.f, 0.f};   // cols n=16..31 (g|o)
      auto MM2 = [&](short8 a, const u16* Ws, int kk) {
        const u16* bb = Ws + (kk * 4 + q) * 256 + l15 * 8;
        short8 b0 = *(const short8*)bb;
        short8 b1 = *(const short8*)(bb + 128);
        acc0 = __builtin_amdgcn_mfma_f32_16x16x32_bf16(a, b0, acc0, 0, 0, 0);
        acc1 = __builtin_amdgcn_mfma_f32_16x16x32_bf16(a, b1, acc1, 0, 0, 0);
      };

      if (layer == 0) {
        #pragma unroll
        for (int kk = 0; kk < 8; ++kk) MM2(xfr[kk], Ws_in, kk);
      } else {
        #pragma unroll
        for (int kk = 0; kk < 16; ++kk) MM2(mk8(ilo[kk], ihi[kk]), Ws_in, kk);
      }
      if (t > 0) {
        #pragma unroll
        for (int kk = 0; kk < 16; ++kk) MM2(mk8(rlo[kk], rhi[kk]), Ws_rec, kk);
      }

      // ---- gate epilogue: D layout col=lane&15,row=q*4+r; lanes n<8 hold i,g; n>=8 hold f,o ----
      u16* hw = ownbuf + (size_t)(t & 1) * SLOT;
      const bool low = (l15 < 8);
      #pragma unroll
      for (int r = 0; r < 4; ++r) {
        float a0 = acc0[r], a1 = acc1[r];
        float p0 = __shfl_xor(a0, 8);
        float p1 = __shfl_xor(a1, 8);
        float iv = low ? a0 : p0;
        float fv = low ? p0 : a0;
        float gv = low ? a1 : p1;
        float ov = low ? p1 : a1;
        iv = sigm(iv + bi_i);
        fv = sigm(fv + bi_f);
        gv = ftanh(gv + bi_g);
        ov = sigm(ov + bi_o);
        float cn = fv * cst[r] + iv * gv;
        cst[r] = cn;
        float hv = ov * ftanh(cn);
        if (low) cstore2(&hw[(size_t)(wmbase + q * 4 + r) * HDIM + jbase + cc], f2bf(hv));
      }
    }
    grid_barrier(cnt, root, rel, it, tid, bid);
  }

  // ---- FC epilogue: out[b] = sigmoid(h2[b,:] . w_fc + b_fc); h1_t=511 is in parity 1 ----
  if (bid == NWG - 1) {
    __builtin_amdgcn_fence(__ATOMIC_ACQUIRE, "agent");
    const int b = tid >> 1, half = tid & 1;
    const u16* hp = h1buf + (size_t)1 * SLOT + (size_t)b * HDIM + half * 256;
    const float* wf = wfc + half * 256;
    float s = 0.f;
    for (int k = 0; k < 256; ++k) s += bf2f(hp[k]) * wf[k];
    s += __shfl_xor(s, 1);
    if (half == 0) out[b] = sigm(s + bfc[0]);
  }
}

extern "C" void kernel_launch(void* const* d_in, const int* in_sizes, int n_in,
                              void* d_out, int out_size, void* d_ws, size_t ws_size,
                              hipStream_t stream) {
  (void)in_sizes; (void)n_in; (void)out_size; (void)ws_size;
  const float* x    = (const float*)d_in[0];
  const float* wih0 = (const float*)d_in[1];
  const float* whh0 = (const float*)d_in[2];
  const float* bih0 = (const float*)d_in[3];
  const float* bhh0 = (const float*)d_in[4];
  const float* wih1 = (const float*)d_in[5];
  const float* whh1 = (const float*)d_in[6];
  const float* bih1 = (const float*)d_in[7];
  const float* bhh1 = (const float*)d_in[8];
  const float* wfc  = (const float*)d_in[9];
  const float* bfc  = (const float*)d_in[10];
  float* outp = (float*)d_out;

  char* ws = (char*)d_ws;
  int*  cnt  = (int*)ws;                                       // 8 sub-counters, 256B apart
  int*  root = (int*)(ws + 2048);                              // root counter
  int*  rel  = (int*)(ws + 2176);                              // release epoch word
  u16*  xbf  = (u16*)(ws + 4096);                              // 128*512*256 bf16 = 32 MiB
  u16*  h0   = (u16*)(ws + 4096 + 33554432);                   // [2][128][512] bf16
  u16*  h1   = h0 + 2 * SLOT;                                  // [2][128][512] bf16

  hipMemsetAsync(d_ws, 0, 4096, stream);                       // zero barrier state

  const int n4 = (BATCH * T_STEPS * EDIM) / 4;                 // 4,194,304
  cvt_bf16_kernel<<<n4 / 256, 256, 0, stream>>>(x, xbf, n4);

  hipFuncSetAttribute((const void*)lstm_kernel,
                      hipFuncAttributeMaxDynamicSharedMemorySize, 65536);

  void* args[] = { (void*)&wih0, (void*)&whh0, (void*)&bih0, (void*)&bhh0,
                   (void*)&wih1, (void*)&whh1, (void*)&bih1, (void*)&bhh1,
                   (void*)&wfc,  (void*)&bfc,
                   (void*)&xbf,  (void*)&h0,   (void*)&h1,
                   (void*)&outp, (void*)&cnt,  (void*)&root, (void*)&rel };
  hipLaunchCooperativeKernel((void*)lstm_kernel, dim3(NWG), dim3(WGS),
                             args, 65536, stream);
}

// Round 8
// 3368.698 us; speedup vs baseline: 2.5228x; 1.6256x over previous
//
#include <hip/hip_runtime.h>

using u16    = unsigned short;
using u64_t  = unsigned long long;
using short4v = __attribute__((ext_vector_type(4))) short;
using short8 = __attribute__((ext_vector_type(8))) short;
using f32x4  = __attribute__((ext_vector_type(4))) float;

#define T_STEPS 512
#define BATCH   128
#define HDIM    512
#define EDIM    256
#define NWG     256
#define WGS     256
// packed h: [parity][cg(64)][row(128)][8 cols] bf16 -> 64*128*8 u16 per parity
#define HPITCH  65536

__device__ __forceinline__ u16 f2bf(float f) {
  unsigned u = __float_as_uint(f);
  u += 0x7FFFu + ((u >> 16) & 1u);   // RNE
  return (u16)(u >> 16);
}
__device__ __forceinline__ float bf2f(u16 h) {
  return __uint_as_float(((unsigned)h) << 16);
}
__device__ __forceinline__ float sigm(float x) { return 1.0f / (1.0f + __expf(-x)); }
__device__ __forceinline__ float ftanh(float x) { return 1.0f - 2.0f / (__expf(2.0f * x) + 1.0f); }

// ---- coherent (agent-scope, sc0|sc1) accessors: LLC-coherent, no L2 flush ----
__device__ __forceinline__ u64_t cl8(const u16* p) {
  return __hip_atomic_load((const u64_t*)p, __ATOMIC_RELAXED, __HIP_MEMORY_SCOPE_AGENT);
}
__device__ __forceinline__ void cstore2(u16* p, u16 v) {
  __hip_atomic_store(p, v, __ATOMIC_RELAXED, __HIP_MEMORY_SCOPE_AGENT);
}
__device__ __forceinline__ short8 mk8(u64_t lo, u64_t hi) {
  short4v a = __builtin_bit_cast(short4v, lo);
  short4v b = __builtin_bit_cast(short4v, hi);
  return __builtin_shufflevector(a, b, 0, 1, 2, 3, 4, 5, 6, 7);
}

// ---------------- x -> bf16 prep ----------------
__global__ void cvt_bf16_kernel(const float* __restrict__ src, u16* __restrict__ dst, int n4) {
  int i = blockIdx.x * blockDim.x + threadIdx.x;
  if (i >= n4) return;
  float4 v = ((const float4*)src)[i];
  uint2 o;
  o.x = (unsigned)f2bf(v.x) | ((unsigned)f2bf(v.y) << 16);
  o.y = (unsigned)f2bf(v.z) | ((unsigned)f2bf(v.w) << 16);
  ((uint2*)dst)[i] = o;
}

// ---------------- grid barrier: arrival tree + release word ----------------
// Entry __syncthreads drains vmcnt(0) per wave -> all sc1 h-stores are LLC-visible
// before tid0's arrival add. tid0 polls the release word with s_sleep(1); sibling
// waves wait at the exit s_barrier. Monotone epochs; no re-arm.
__device__ __forceinline__ void grid_barrier(int* cnt, int* root, int* rel,
                                             int it, int tid, int bid) {
  __syncthreads();
  if (tid == 0) {
    int* mycnt = cnt + (bid >> 5) * 64;   // 8 sub-counters, 256B apart
    int old = __hip_atomic_fetch_add(mycnt, 1, __ATOMIC_RELAXED, __HIP_MEMORY_SCOPE_AGENT);
    if (old == 32 * (it + 1) - 1) {
      int r = __hip_atomic_fetch_add(root, 1, __ATOMIC_RELAXED, __HIP_MEMORY_SCOPE_AGENT);
      if (r == 8 * (it + 1) - 1)
        __hip_atomic_store(rel, it + 1, __ATOMIC_RELAXED, __HIP_MEMORY_SCOPE_AGENT);
    }
    while (__hip_atomic_load(rel, __ATOMIC_RELAXED, __HIP_MEMORY_SCOPE_AGENT) < it + 1)
      __builtin_amdgcn_s_sleep(1);
  }
  __syncthreads();
}

// ---------------- persistent 2-layer LSTM ----------------
// WG tile: 64 batch rows (mhalf) x 8 h-cols (nc) -> 32 gate rows [i(8) f(8) g(8) o(8)].
// LDS: Ws_in [K_in/8][32][8] bf16 (32KB), Ws_rec [64][32][8] bf16 (32KB) = 64KB dynamic.
// h exchange is PACKED: h[parity][cg][row][8] so each WG writes a dense 1KB block
// and consumers load 256B-dense chunks (no partial-line HBM RMW).
__global__ void __launch_bounds__(WGS, 1) lstm_kernel(
    const float* __restrict__ wih0, const float* __restrict__ whh0,
    const float* __restrict__ bih0, const float* __restrict__ bhh0,
    const float* __restrict__ wih1, const float* __restrict__ whh1,
    const float* __restrict__ bih1, const float* __restrict__ bhh1,
    const float* __restrict__ wfc,  const float* __restrict__ bfc,
    const u16* __restrict__ xbf, u16* __restrict__ h0buf, u16* __restrict__ h1buf,
    float* __restrict__ out, int* cnt, int* root, int* rel)
{
  extern __shared__ u16 smem[];
  u16* Ws_in  = smem;            // [K_in/8][32][8]
  u16* Ws_rec = smem + 16384;    // [64][32][8]

  const int tid    = threadIdx.x;
  const int bid    = blockIdx.x;
  const int layer  = bid >> 7;          // 0..1
  const int lb     = bid & 127;
  const int mhalf  = lb & 1;            // batch half
  const int nc     = lb >> 1;           // 0..63 -> 8 h-cols each
  const int jbase  = nc * 8;
  const int w      = tid >> 6;          // wave 0..3 -> 16 batch rows each
  const int lane   = tid & 63;
  const int l15    = lane & 15;
  const int q      = lane >> 4;
  const int wmbase = mhalf * 64 + w * 16;

  const int K_in = layer ? HDIM : EDIM;
  const float* Wih = layer ? wih1 : wih0;
  const float* Whh = layer ? whh1 : whh0;
  const float* Bih = layer ? bih1 : bih0;
  const float* Bhh = layer ? bhh1 : bhh0;

  // ---- one-time: stage weight slices to LDS as bf16, layout [k/8][n][8] ----
  for (int p = tid; p < 32 * (K_in / 8); p += WGS) {
    int c = p >> 5, n = p & 31;
    int grow = (n >> 3) * HDIM + jbase + (n & 7);     // gate*512 + col
    const float* s = Wih + (size_t)grow * K_in + c * 8;
    u16* d = Ws_in + p * 8;
    #pragma unroll
    for (int e = 0; e < 8; ++e) d[e] = f2bf(s[e]);
  }
  for (int p = tid; p < 32 * (HDIM / 8); p += WGS) {
    int c = p >> 5, n = p & 31;
    int grow = (n >> 3) * HDIM + jbase + (n & 7);
    const float* s = Whh + (size_t)grow * HDIM + c * 8;
    u16* d = Ws_rec + p * 8;
    #pragma unroll
    for (int e = 0; e < 8; ++e) d[e] = f2bf(s[e]);
  }

  // per-lane biases for column cc = l15&7 (lanes n and n+8 duplicate the same column)
  const int cc = l15 & 7;
  const float bi_i = Bih[0*HDIM + jbase + cc] + Bhh[0*HDIM + jbase + cc];
  const float bi_f = Bih[1*HDIM + jbase + cc] + Bhh[1*HDIM + jbase + cc];
  const float bi_g = Bih[2*HDIM + jbase + cc] + Bhh[2*HDIM + jbase + cc];
  const float bi_o = Bih[3*HDIM + jbase + cc] + Bhh[3*HDIM + jbase + cc];

  __syncthreads();

  float cst[4] = {0.f, 0.f, 0.f, 0.f};   // c-state: 4 rows (q*4+r) x col cc
  u16* ownbuf = layer ? h1buf : h0buf;
  const int arow = wmbase + l15;
  // packed per-(q,row) consumer base offset: ((q*128)+arow)*8 ; per kk add 4096
  const size_t cbase = ((size_t)q * 128 + arow) * 8;

  for (int it = 0; it <= T_STEPS; ++it) {
    const int t = layer ? (it - 1) : it;
    if (t >= 0 && t < T_STEPS) {
      // ======== BATCHED LOAD PHASE: all h-frag loads issued back-to-back ========
      u64_t ilo[16], ihi[16];   // input-GEMM frags (layer 1 only; layer 0 uses xfr)
      u64_t rlo[16], rhi[16];   // recurrent frags
      short8 xfr[8];            // layer-0 x frags (plain cached loads)

      if (layer == 1) {
        const u16* ab = h0buf + (size_t)(t & 1) * HPITCH + cbase;
        #pragma unroll
        for (int kk = 0; kk < 16; ++kk) {
          ilo[kk] = cl8(ab + kk * 4096);
          ihi[kk] = cl8(ab + kk * 4096 + 4);
        }
      }
      if (t > 0) {
        const u16* rb = ownbuf + (size_t)((t - 1) & 1) * HPITCH + cbase;
        #pragma unroll
        for (int kk = 0; kk < 16; ++kk) {
          rlo[kk] = cl8(rb + kk * 4096);
          rhi[kk] = cl8(rb + kk * 4096 + 4);
        }
      }
      if (layer == 0) {
        const u16* xb = xbf + ((size_t)arow * T_STEPS + t) * EDIM + q * 8;
        #pragma unroll
        for (int kk = 0; kk < 8; ++kk) xfr[kk] = *(const short8*)(xb + kk * 32);
      }

      // ======== MFMA PHASE ========
      f32x4 acc0 = {0.f, 0.f, 0.f, 0.f};   // cols n=0..15  (i|f)
      f32x4 acc1 = {0.f, 0.f, 0.f, 0.f};   // cols n=16..31 (g|o)
      auto MM2 = [&](short8 a, const u16* Ws, int kk) {
        const u16* bb = Ws + (kk * 4 + q) * 256 + l15 * 8;
        short8 b0 = *(const short8*)bb;
        short8 b1 = *(const short8*)(bb + 128);
        acc0 = __builtin_amdgcn_mfma_f32_16x16x32_bf16(a, b0, acc0, 0, 0, 0);
        acc1 = __builtin_amdgcn_mfma_f32_16x16x32_bf16(a, b1, acc1, 0, 0, 0);
      };

      if (layer == 0) {
        #pragma unroll
        for (int kk = 0; kk < 8; ++kk) MM2(xfr[kk], Ws_in, kk);
      } else {
        #pragma unroll
        for (int kk = 0; kk < 16; ++kk) MM2(mk8(ilo[kk], ihi[kk]), Ws_in, kk);
      }
      if (t > 0) {
        #pragma unroll
        for (int kk = 0; kk < 16; ++kk) MM2(mk8(rlo[kk], rhi[kk]), Ws_rec, kk);
      }

      // ---- gate epilogue: D layout col=lane&15,row=q*4+r; lanes n<8 hold i,g; n>=8 hold f,o ----
      u16* hw = ownbuf + (size_t)(t & 1) * HPITCH + (size_t)nc * 1024;  // [cg][row][8]
      const bool low = (l15 < 8);
      #pragma unroll
      for (int r = 0; r < 4; ++r) {
        float a0 = acc0[r], a1 = acc1[r];
        float p0 = __shfl_xor(a0, 8);
        float p1 = __shfl_xor(a1, 8);
        float iv = low ? a0 : p0;
        float fv = low ? p0 : a0;
        float gv = low ? a1 : p1;
        float ov = low ? p1 : a1;
        iv = sigm(iv + bi_i);
        fv = sigm(fv + bi_f);
        gv = ftanh(gv + bi_g);
        ov = sigm(ov + bi_o);
        float cn = fv * cst[r] + iv * gv;
        cst[r] = cn;
        float hv = ov * ftanh(cn);
        if (low) cstore2(&hw[(size_t)(wmbase + q * 4 + r) * 8 + cc], f2bf(hv));
      }
    }
    grid_barrier(cnt, root, rel, it, tid, bid);
  }

  // ---- FC epilogue: out[b] = sigmoid(h2[b,:] . w_fc + b_fc); h1_t=511 is in parity 1 ----
  if (bid == NWG - 1) {
    __builtin_amdgcn_fence(__ATOMIC_ACQUIRE, "agent");
    const int b = tid >> 1, half = tid & 1;
    const u16* hp = h1buf + HPITCH;          // parity 1, packed [cg][row][8]
    const float* wf = wfc + half * 256;
    float s = 0.f;
    for (int cg = 0; cg < 32; ++cg) {
      const u16* p = hp + ((size_t)(half * 32 + cg) * 128 + b) * 8;
      #pragma unroll
      for (int e = 0; e < 8; ++e) s += bf2f(p[e]) * wf[cg * 8 + e];
    }
    s += __shfl_xor(s, 1);
    if (half == 0) out[b] = sigm(s + bfc[0]);
  }
}

extern "C" void kernel_launch(void* const* d_in, const int* in_sizes, int n_in,
                              void* d_out, int out_size, void* d_ws, size_t ws_size,
                              hipStream_t stream) {
  (void)in_sizes; (void)n_in; (void)out_size; (void)ws_size;
  const float* x    = (const float*)d_in[0];
  const float* wih0 = (const float*)d_in[1];
  const float* whh0 = (const float*)d_in[2];
  const float* bih0 = (const float*)d_in[3];
  const float* bhh0 = (const float*)d_in[4];
  const float* wih1 = (const float*)d_in[5];
  const float* whh1 = (const float*)d_in[6];
  const float* bih1 = (const float*)d_in[7];
  const float* bhh1 = (const float*)d_in[8];
  const float* wfc  = (const float*)d_in[9];
  const float* bfc  = (const float*)d_in[10];
  float* outp = (float*)d_out;

  char* ws = (char*)d_ws;
  int*  cnt  = (int*)ws;                                       // 8 sub-counters, 256B apart
  int*  root = (int*)(ws + 2048);                              // root counter
  int*  rel  = (int*)(ws + 2176);                              // release epoch word
  u16*  xbf  = (u16*)(ws + 4096);                              // 128*512*256 bf16 = 32 MiB
  u16*  h0   = (u16*)(ws + 4096 + 33554432);                   // packed [2][64][128][8] bf16
  u16*  h1   = h0 + 2 * HPITCH;                                // packed [2][64][128][8] bf16

  hipMemsetAsync(d_ws, 0, 4096, stream);                       // zero barrier state

  const int n4 = (BATCH * T_STEPS * EDIM) / 4;                 // 4,194,304
  cvt_bf16_kernel<<<n4 / 256, 256, 0, stream>>>(x, xbf, n4);

  hipFuncSetAttribute((const void*)lstm_kernel,
                      hipFuncAttributeMaxDynamicSharedMemorySize, 65536);

  void* args[] = { (void*)&wih0, (void*)&whh0, (void*)&bih0, (void*)&bhh0,
                   (void*)&wih1, (void*)&whh1, (void*)&bih1, (void*)&bhh1,
                   (void*)&wfc,  (void*)&bfc,
                   (void*)&xbf,  (void*)&h0,   (void*)&h1,
                   (void*)&outp, (void*)&cnt,  (void*)&root, (void*)&rel };
  hipLaunchCooperativeKernel((void*)lstm_kernel, dim3(NWG), dim3(WGS),
                             args, 65536, stream);
}